// Round 3
// baseline (235.513 us; speedup 1.0000x reference)
//
#include <hip/hip_runtime.h>

// MoE GLU MLP: E=8, D=1024, H=1024, K=2, N=2048 tokens, 4096 pairs.
// 3 kernels: prep (bucket + x->bf16 + W1^T/W2^T->bf16 + zero out),
//            gemm1 (x@W1 + SiLU-GLU, BK=64),
//            gemm2 (act@W2, fused gate-weighted atomic combine into out).

typedef __bf16 bf16x8 __attribute__((ext_vector_type(8)));
typedef __bf16 bf16x4 __attribute__((ext_vector_type(4)));
typedef float  f32x4  __attribute__((ext_vector_type(4)));

#define NPAIR 4096
#define NTOK  2048
#define DDIM  1024
#define HDIM  1024
#define NEXP  8

// workspace layout (bytes)
#define ORDER_I   64                      // int index of order[] in wsi
#define XB_OFF    (24576)                 // bf16 x        [2048][1024]   4 MB
#define W1T_OFF   (XB_OFF + 4194304)      // bf16 W1^T  [8][2048][1024]  32 MB
#define W2T_OFF   (W1T_OFF + 33554432)    // bf16 W2^T  [8][1024][1024]  16 MB
#define ACT_OFF   (W2T_OFF + 16777216)    // bf16 act      [5120][1024] 10.5 MB

#define GLOAD_LDS16(g, l) \
    __builtin_amdgcn_global_load_lds( \
        (const __attribute__((address_space(1))) void*)(g), \
        (__attribute__((address_space(3))) void*)(l), 16, 0, 0)

// ---------------- prep: one kernel, block-level job dispatch ----------------
// blocks [0,4096):      W1 transpose-convert tiles (64x64)
// blocks [4096,6144):   W2 transpose-convert tiles
// blocks [6144,8192):   x -> bf16 chunks (1024 elems)
// blocks [8192,8704):   zero d_out chunks (4096 floats)
// block  8704:          bucket (counts/offsets/order)
__device__ __forceinline__ void tcvt_tile(const float* __restrict__ s,
                                          __bf16* __restrict__ d,
                                          int R, int C, int r0, int c0,
                                          float (*t)[65], int tid) {
    const int lr = tid >> 4;            // 0..15
    const int lc = (tid & 15) * 4;      // 0..60
#pragma unroll
    for (int p = 0; p < 4; p++) {
        int r = p * 16 + lr;
        float4 v = *(const float4*)(s + (size_t)(r0 + r) * C + c0 + lc);
        t[r][lc] = v.x; t[r][lc + 1] = v.y; t[r][lc + 2] = v.z; t[r][lc + 3] = v.w;
    }
    __syncthreads();
#pragma unroll
    for (int p = 0; p < 4; p++) {
        int c = p * 16 + lr;
        bf16x4 o;
#pragma unroll
        for (int i = 0; i < 4; i++) o[i] = (__bf16)t[lc + i][c];
        *(bf16x4*)(d + (size_t)(c0 + c) * R + r0 + lc) = o;
    }
}

__global__ __launch_bounds__(256) void prep_kernel(const float* __restrict__ x,
                                                   const float* __restrict__ W1,
                                                   const float* __restrict__ W2,
                                                   const int* __restrict__ idx,
                                                   int* __restrict__ wsi,
                                                   __bf16* __restrict__ xb,
                                                   __bf16* __restrict__ w1t,
                                                   __bf16* __restrict__ w2t,
                                                   float* __restrict__ out) {
    __shared__ float t[64][65];
    __shared__ int cnt[NEXP], base[NEXP], cur[NEXP];
    const int b = blockIdx.x;
    const int tid = threadIdx.x;
    if (b < 4096) {
        // W1: R=1024 (d), C=2048 (n); 512 tiles/expert = 32 c-tiles x 16 r-tiles
        int e = b >> 9, tt = b & 511;
        int c0 = (tt & 31) * 64, r0 = (tt >> 5) * 64;
        tcvt_tile(W1 + (size_t)e * DDIM * 2 * HDIM, w1t + (size_t)e * 2 * HDIM * DDIM,
                  DDIM, 2 * HDIM, r0, c0, t, tid);
    } else if (b < 6144) {
        // W2: R=1024 (h), C=1024 (n); 256 tiles/expert
        int b2 = b - 4096;
        int e = b2 >> 8, tt = b2 & 255;
        int c0 = (tt & 15) * 64, r0 = (tt >> 4) * 64;
        tcvt_tile(W2 + (size_t)e * HDIM * DDIM, w2t + (size_t)e * DDIM * HDIM,
                  HDIM, DDIM, r0, c0, t, tid);
    } else if (b < 8192) {
        int i = (b - 6144) * 1024 + tid * 4;
        float4 v = *(const float4*)(x + i);
        bf16x4 o;
        o[0] = (__bf16)v.x; o[1] = (__bf16)v.y; o[2] = (__bf16)v.z; o[3] = (__bf16)v.w;
        *(bf16x4*)(xb + i) = o;
    } else if (b < 8704) {
        int base4 = (b - 8192) * 4096;
        float4 z = {0.f, 0.f, 0.f, 0.f};
#pragma unroll
        for (int j = 0; j < 4; j++)
            *(float4*)(out + base4 + j * 1024 + tid * 4) = z;
    } else {
        if (tid < NEXP) { cnt[tid] = 0; cur[tid] = 0; }
        __syncthreads();
        for (int i = tid; i < NPAIR; i += 256) atomicAdd(&cnt[idx[i] & 7], 1);
        __syncthreads();
        if (tid == 0) {
            int off = 0;
            for (int e = 0; e < NEXP; e++) {
                base[e] = off;
                wsi[e] = cnt[e];
                wsi[8 + e] = off;
                off += (cnt[e] + 127) & ~127;
            }
        }
        __syncthreads();
        for (int i = tid; i < NPAIR; i += 256) {
            int e = idx[i] & 7;
            int s = atomicAdd(&cur[e], 1);
            wsi[ORDER_I + base[e] + s] = i;
        }
    }
}

// ---------------- gemm1: 128m x 64 out-cols (128 B-rows: h+g interleaved), BK=64
__global__ __launch_bounds__(256) void gemm1_kernel(const __bf16* __restrict__ xb,
                                                    const __bf16* __restrict__ w1t,
                                                    const int* __restrict__ wsi,
                                                    __bf16* __restrict__ act) {
    const int e = blockIdx.z;
    const int cnt = wsi[e];
    const int m0 = blockIdx.y * 128;
    if (m0 >= cnt) return;
    const int base = wsi[8 + e];
    const int n0 = blockIdx.x * 64;
    const int* order = wsi + ORDER_I;
    const __bf16* w1e = w1t + (size_t)e * 2048 * 1024;

    __shared__ __align__(16) __bf16 As[128][64];
    __shared__ __align__(16) __bf16 Bs[128][64];

    const int tid = threadIdx.x;
    const int lane = tid & 63, w = tid >> 6;
    const int lm = lane & 15, q = lane >> 4;
    const int wm = w & 1, wn = w >> 1;

    // 4 A + 4 B staging chunks per thread; chunk c -> row c>>3, k-off (c&7)*8
    const __bf16* ga[4];
    const __bf16* gb[4];
#pragma unroll
    for (int j = 0; j < 4; j++) {
        int c = j * 256 + tid;
        int r = c >> 3, ks = (c & 7) * 8;
        int m = m0 + r; if (m >= cnt) m = cnt - 1;
        int tok = order[base + m] >> 1;
        ga[j] = xb + (size_t)tok * DDIM + ks;
        int half = r >> 6, rr = r & 63;
        int rb = (rr < 32) ? (n0 + half * 32 + rr)
                           : (HDIM + n0 + half * 32 + (rr - 32));
        gb[j] = w1e + (size_t)rb * DDIM + ks;
    }

    f32x4 acc[4][4];
#pragma unroll
    for (int mt = 0; mt < 4; mt++)
#pragma unroll
        for (int nt = 0; nt < 4; nt++) acc[mt][nt] = (f32x4){0.f, 0.f, 0.f, 0.f};

    for (int k0 = 0; k0 < DDIM; k0 += 64) {
        __syncthreads();
#pragma unroll
        for (int j = 0; j < 4; j++) {
            int c = j * 256 + tid;
            GLOAD_LDS16(ga[j], (char*)&As[0][0] + c * 16);
            GLOAD_LDS16(gb[j], (char*)&Bs[0][0] + c * 16);
            ga[j] += 64; gb[j] += 64;
        }
        __syncthreads();
#pragma unroll
        for (int kh = 0; kh < 2; kh++) {
            bf16x8 af[4];
#pragma unroll
            for (int mt = 0; mt < 4; mt++)
                af[mt] = *(const bf16x8*)(&As[wm * 64 + mt * 16 + lm][kh * 32 + q * 8]);
#pragma unroll
            for (int nt = 0; nt < 4; nt++) {
                bf16x8 bfr = *(const bf16x8*)(&Bs[wn * 64 + nt * 16 + lm][kh * 32 + q * 8]);
#pragma unroll
                for (int mt = 0; mt < 4; mt++)
                    acc[mt][nt] = __builtin_amdgcn_mfma_f32_16x16x32_bf16(af[mt], bfr, acc[mt][nt], 0, 0, 0);
            }
        }
    }

#pragma unroll
    for (int mt = 0; mt < 4; mt++) {
        int mbase = m0 + wm * 64 + mt * 16 + q * 4;
#pragma unroll
        for (int ntp = 0; ntp < 2; ntp++) {
            int col = n0 + wn * 32 + ntp * 16 + lm;
#pragma unroll
            for (int r = 0; r < 4; r++) {
                int m = mbase + r;
                if (m < cnt) {
                    float h = acc[mt][ntp][r];
                    float g = acc[mt][ntp + 2][r];
                    float a = h * (g / (1.f + __expf(-g)));
                    act[(size_t)(base + m) * HDIM + col] = (__bf16)a;
                }
            }
        }
    }
}

// ---------------- gemm2: 128m x 64n, BK=64, fused p-weighted atomic combine
__global__ __launch_bounds__(256) void gemm2_kernel(const __bf16* __restrict__ act,
                                                    const __bf16* __restrict__ w2t,
                                                    const int* __restrict__ wsi,
                                                    const float* __restrict__ p,
                                                    float* __restrict__ out) {
    const int e = blockIdx.z;
    const int cnt = wsi[e];
    const int m0 = blockIdx.y * 128;
    if (m0 >= cnt) return;
    const int base = wsi[8 + e];
    const int n0 = blockIdx.x * 64;
    const int* order = wsi + ORDER_I;
    const __bf16* w2e = w2t + (size_t)e * 1024 * 1024;

    __shared__ __align__(16) __bf16 As[128][64];
    __shared__ __align__(16) __bf16 Bs[64][64];

    const int tid = threadIdx.x;
    const int lane = tid & 63, w = tid >> 6;
    const int lm = lane & 15, q = lane >> 4;
    const int wm = w & 1, wn = w >> 1;

    const __bf16* ga[4];
    const __bf16* gb[2];
#pragma unroll
    for (int j = 0; j < 4; j++) {
        int c = j * 256 + tid;
        int r = c >> 3, ks = (c & 7) * 8;
        ga[j] = act + (size_t)(base + m0 + r) * HDIM + ks;  // pad rows masked at epilogue
    }
#pragma unroll
    for (int j = 0; j < 2; j++) {
        int c = j * 256 + tid;
        int r = c >> 3, ks = (c & 7) * 8;
        gb[j] = w2e + (size_t)(n0 + r) * HDIM + ks;
    }

    f32x4 acc[4][2];
#pragma unroll
    for (int mt = 0; mt < 4; mt++)
#pragma unroll
        for (int nt = 0; nt < 2; nt++) acc[mt][nt] = (f32x4){0.f, 0.f, 0.f, 0.f};

    for (int k0 = 0; k0 < HDIM; k0 += 64) {
        __syncthreads();
#pragma unroll
        for (int j = 0; j < 4; j++) {
            int c = j * 256 + tid;
            GLOAD_LDS16(ga[j], (char*)&As[0][0] + c * 16);
            ga[j] += 64;
        }
#pragma unroll
        for (int j = 0; j < 2; j++) {
            int c = j * 256 + tid;
            GLOAD_LDS16(gb[j], (char*)&Bs[0][0] + c * 16);
            gb[j] += 64;
        }
        __syncthreads();
#pragma unroll
        for (int kh = 0; kh < 2; kh++) {
            bf16x8 af[4];
#pragma unroll
            for (int mt = 0; mt < 4; mt++)
                af[mt] = *(const bf16x8*)(&As[wm * 64 + mt * 16 + lm][kh * 32 + q * 8]);
#pragma unroll
            for (int nt = 0; nt < 2; nt++) {
                bf16x8 bfr = *(const bf16x8*)(&Bs[wn * 32 + nt * 16 + lm][kh * 32 + q * 8]);
#pragma unroll
                for (int mt = 0; mt < 4; mt++)
                    acc[mt][nt] = __builtin_amdgcn_mfma_f32_16x16x32_bf16(af[mt], bfr, acc[mt][nt], 0, 0, 0);
            }
        }
    }

    // fused combine: out[tok] += p[pair] * acc  (out zeroed by prep)
    int pi[4][4];
    float pw[4][4];
#pragma unroll
    for (int mt = 0; mt < 4; mt++)
#pragma unroll
        for (int r = 0; r < 4; r++) {
            int gm = m0 + wm * 64 + mt * 16 + q * 4 + r;
            if (gm < cnt) {
                int pr = order[base + gm];
                pi[mt][r] = pr;
                pw[mt][r] = p[pr];
            } else pi[mt][r] = -1;
        }
#pragma unroll
    for (int mt = 0; mt < 4; mt++)
#pragma unroll
        for (int nt = 0; nt < 2; nt++) {
            int col = n0 + wn * 32 + nt * 16 + lm;
#pragma unroll
            for (int r = 0; r < 4; r++) {
                if (pi[mt][r] >= 0) {
                    int tok = pi[mt][r] >> 1;
                    atomicAdd(out + (size_t)tok * DDIM + col, pw[mt][r] * acc[mt][nt][r]);
                }
            }
        }
}

extern "C" void kernel_launch(void* const* d_in, const int* in_sizes, int n_in,
                              void* d_out, int out_size, void* d_ws, size_t ws_size,
                              hipStream_t stream) {
    (void)in_sizes; (void)n_in; (void)out_size; (void)ws_size;
    const float* x   = (const float*)d_in[0];
    const float* p   = (const float*)d_in[1];
    const int* eidx  = (const int*)d_in[2];
    const float* W1  = (const float*)d_in[3];
    const float* W2  = (const float*)d_in[4];
    float* out = (float*)d_out;

    char* ws = (char*)d_ws;
    int* wsi     = (int*)ws;
    __bf16* xb   = (__bf16*)(ws + XB_OFF);
    __bf16* w1t  = (__bf16*)(ws + W1T_OFF);
    __bf16* w2t  = (__bf16*)(ws + W2T_OFF);
    __bf16* act  = (__bf16*)(ws + ACT_OFF);

    prep_kernel<<<8705, 256, 0, stream>>>(x, W1, W2, eidx, wsi, xb, w1t, w2t, out);
    gemm1_kernel<<<dim3(16, 32, NEXP), 256, 0, stream>>>(xb, w1t, wsi, act);
    gemm2_kernel<<<dim3(16, 32, NEXP), 256, 0, stream>>>(act, w2t, wsi, p, out);
}

// Round 4
// 222.335 us; speedup vs baseline: 1.0593x; 1.0593x over previous
//
#include <hip/hip_runtime.h>

// MoE GLU MLP: E=8, D=1024, H=1024, K=2, N=2048 tokens, 4096 pairs.
// 3 kernels: prep (bucket + x->bf16 + W1^T/W2^T->bf16 + zero out),
//            gemm1 (x@W1 + SiLU-GLU, BK=64, XOR-swizzled LDS),
//            gemm2 (act@W2, fused gate-weighted atomic combine, swizzled LDS).
// LDS swizzle: logical k-chunk kb of row r lives at physical slot kb^(r&7);
// fragment reads then spread all 8 bank-groups (2 lanes/bank = free).

typedef __bf16 bf16x8 __attribute__((ext_vector_type(8)));
typedef __bf16 bf16x4 __attribute__((ext_vector_type(4)));
typedef float  f32x4  __attribute__((ext_vector_type(4)));

#define NPAIR 4096
#define NTOK  2048
#define DDIM  1024
#define HDIM  1024
#define NEXP  8

// workspace layout (bytes)
#define ORDER_I   64                      // int index of order[] in wsi
#define XB_OFF    (24576)                 // bf16 x        [2048][1024]   4 MB
#define W1T_OFF   (XB_OFF + 4194304)      // bf16 W1^T  [8][2048][1024]  32 MB
#define W2T_OFF   (W1T_OFF + 33554432)    // bf16 W2^T  [8][1024][1024]  16 MB
#define ACT_OFF   (W2T_OFF + 16777216)    // bf16 act      [5120][1024] 10.5 MB

#define GLOAD_LDS16(g, l) \
    __builtin_amdgcn_global_load_lds( \
        (const __attribute__((address_space(1))) void*)(g), \
        (__attribute__((address_space(3))) void*)(l), 16, 0, 0)

// ---------------- prep: one kernel, block-level job dispatch ----------------
__device__ __forceinline__ void tcvt_tile(const float* __restrict__ s,
                                          __bf16* __restrict__ d,
                                          int R, int C, int r0, int c0,
                                          float (*t)[65], int tid) {
    const int lr = tid >> 4;            // 0..15
    const int lc = (tid & 15) * 4;      // 0..60
#pragma unroll
    for (int p = 0; p < 4; p++) {
        int r = p * 16 + lr;
        float4 v = *(const float4*)(s + (size_t)(r0 + r) * C + c0 + lc);
        t[r][lc] = v.x; t[r][lc + 1] = v.y; t[r][lc + 2] = v.z; t[r][lc + 3] = v.w;
    }
    __syncthreads();
#pragma unroll
    for (int p = 0; p < 4; p++) {
        int c = p * 16 + lr;
        bf16x4 o;
#pragma unroll
        for (int i = 0; i < 4; i++) o[i] = (__bf16)t[lc + i][c];
        *(bf16x4*)(d + (size_t)(c0 + c) * R + r0 + lc) = o;
    }
}

__global__ __launch_bounds__(256) void prep_kernel(const float* __restrict__ x,
                                                   const float* __restrict__ W1,
                                                   const float* __restrict__ W2,
                                                   const int* __restrict__ idx,
                                                   int* __restrict__ wsi,
                                                   __bf16* __restrict__ xb,
                                                   __bf16* __restrict__ w1t,
                                                   __bf16* __restrict__ w2t,
                                                   float* __restrict__ out) {
    __shared__ float t[64][65];
    __shared__ int cnt[NEXP], base[NEXP], cur[NEXP];
    const int b = blockIdx.x;
    const int tid = threadIdx.x;
    if (b < 4096) {
        int e = b >> 9, tt = b & 511;
        int c0 = (tt & 31) * 64, r0 = (tt >> 5) * 64;
        tcvt_tile(W1 + (size_t)e * DDIM * 2 * HDIM, w1t + (size_t)e * 2 * HDIM * DDIM,
                  DDIM, 2 * HDIM, r0, c0, t, tid);
    } else if (b < 6144) {
        int b2 = b - 4096;
        int e = b2 >> 8, tt = b2 & 255;
        int c0 = (tt & 15) * 64, r0 = (tt >> 4) * 64;
        tcvt_tile(W2 + (size_t)e * HDIM * DDIM, w2t + (size_t)e * DDIM * HDIM,
                  HDIM, DDIM, r0, c0, t, tid);
    } else if (b < 8192) {
        int i = (b - 6144) * 1024 + tid * 4;
        float4 v = *(const float4*)(x + i);
        bf16x4 o;
        o[0] = (__bf16)v.x; o[1] = (__bf16)v.y; o[2] = (__bf16)v.z; o[3] = (__bf16)v.w;
        *(bf16x4*)(xb + i) = o;
    } else if (b < 8704) {
        int base4 = (b - 8192) * 4096;
        float4 z = {0.f, 0.f, 0.f, 0.f};
#pragma unroll
        for (int j = 0; j < 4; j++)
            *(float4*)(out + base4 + j * 1024 + tid * 4) = z;
    } else {
        if (tid < NEXP) { cnt[tid] = 0; cur[tid] = 0; }
        __syncthreads();
        for (int i = tid; i < NPAIR; i += 256) atomicAdd(&cnt[idx[i] & 7], 1);
        __syncthreads();
        if (tid == 0) {
            int off = 0;
            for (int e = 0; e < NEXP; e++) {
                base[e] = off;
                wsi[e] = cnt[e];
                wsi[8 + e] = off;
                off += (cnt[e] + 127) & ~127;
            }
        }
        __syncthreads();
        for (int i = tid; i < NPAIR; i += 256) {
            int e = idx[i] & 7;
            int s = atomicAdd(&cur[e], 1);
            wsi[ORDER_I + base[e] + s] = i;
        }
    }
}

// ---------------- gemm1: 128m x 64 out-cols, BK=64, swizzled LDS
__global__ __launch_bounds__(256) void gemm1_kernel(const __bf16* __restrict__ xb,
                                                    const __bf16* __restrict__ w1t,
                                                    const int* __restrict__ wsi,
                                                    __bf16* __restrict__ act) {
    const int e = blockIdx.z;
    const int cnt = wsi[e];
    const int m0 = blockIdx.y * 128;
    if (m0 >= cnt) return;
    const int base = wsi[8 + e];
    const int n0 = blockIdx.x * 64;
    const int* order = wsi + ORDER_I;
    const __bf16* w1e = w1t + (size_t)e * 2048 * 1024;

    __shared__ __align__(16) __bf16 As[128][64];
    __shared__ __align__(16) __bf16 Bs[128][64];

    const int tid = threadIdx.x;
    const int lane = tid & 63, w = tid >> 6;
    const int lm = lane & 15, q = lane >> 4;
    const int wm = w & 1, wn = w >> 1;
    const int x7 = lm & 7;
    const int sw0 = (q ^ x7) * 16;            // kh=0 byte offset within row
    const int sw1 = ((4 + q) ^ x7) * 16;      // kh=1

    // staging: chunk c -> row c>>3, logical k-chunk kb = (c&7)^(row&7)
    const __bf16* ga[4];
    const __bf16* gb[4];
#pragma unroll
    for (int j = 0; j < 4; j++) {
        int c = j * 256 + tid;
        int r = c >> 3;
        int ks = ((c & 7) ^ (r & 7)) * 8;
        int m = m0 + r; if (m >= cnt) m = cnt - 1;
        int tok = order[base + m] >> 1;
        ga[j] = xb + (size_t)tok * DDIM + ks;
        int half = r >> 6, rr = r & 63;
        int rb = (rr < 32) ? (n0 + half * 32 + rr)
                           : (HDIM + n0 + half * 32 + (rr - 32));
        gb[j] = w1e + (size_t)rb * DDIM + ks;
    }

    f32x4 acc[4][4];
#pragma unroll
    for (int mt = 0; mt < 4; mt++)
#pragma unroll
        for (int nt = 0; nt < 4; nt++) acc[mt][nt] = (f32x4){0.f, 0.f, 0.f, 0.f};

    for (int k0 = 0; k0 < DDIM; k0 += 64) {
        __syncthreads();
#pragma unroll
        for (int j = 0; j < 4; j++) {
            int c = j * 256 + tid;
            GLOAD_LDS16(ga[j], (char*)&As[0][0] + c * 16);
            GLOAD_LDS16(gb[j], (char*)&Bs[0][0] + c * 16);
            ga[j] += 64; gb[j] += 64;
        }
        __syncthreads();
#pragma unroll
        for (int kh = 0; kh < 2; kh++) {
            const int sw = kh ? sw1 : sw0;
            bf16x8 af[4];
#pragma unroll
            for (int mt = 0; mt < 4; mt++)
                af[mt] = *(const bf16x8*)((const char*)&As[wm * 64 + mt * 16 + lm][0] + sw);
#pragma unroll
            for (int nt = 0; nt < 4; nt++) {
                bf16x8 bfr = *(const bf16x8*)((const char*)&Bs[wn * 64 + nt * 16 + lm][0] + sw);
#pragma unroll
                for (int mt = 0; mt < 4; mt++)
                    acc[mt][nt] = __builtin_amdgcn_mfma_f32_16x16x32_bf16(af[mt], bfr, acc[mt][nt], 0, 0, 0);
            }
        }
    }

#pragma unroll
    for (int mt = 0; mt < 4; mt++) {
        int mbase = m0 + wm * 64 + mt * 16 + q * 4;
#pragma unroll
        for (int ntp = 0; ntp < 2; ntp++) {
            int col = n0 + wn * 32 + ntp * 16 + lm;
#pragma unroll
            for (int r = 0; r < 4; r++) {
                int m = mbase + r;
                if (m < cnt) {
                    float h = acc[mt][ntp][r];
                    float g = acc[mt][ntp + 2][r];
                    float a = h * (g / (1.f + __expf(-g)));
                    act[(size_t)(base + m) * HDIM + col] = (__bf16)a;
                }
            }
        }
    }
}

// ---------------- gemm2: 128m x 64n, BK=64, fused p-weighted atomic combine
__global__ __launch_bounds__(256) void gemm2_kernel(const __bf16* __restrict__ act,
                                                    const __bf16* __restrict__ w2t,
                                                    const int* __restrict__ wsi,
                                                    const float* __restrict__ p,
                                                    float* __restrict__ out) {
    const int e = blockIdx.z;
    const int cnt = wsi[e];
    const int m0 = blockIdx.y * 128;
    if (m0 >= cnt) return;
    const int base = wsi[8 + e];
    const int n0 = blockIdx.x * 64;
    const int* order = wsi + ORDER_I;
    const __bf16* w2e = w2t + (size_t)e * 1024 * 1024;

    __shared__ __align__(16) __bf16 As[128][64];
    __shared__ __align__(16) __bf16 Bs[64][64];

    const int tid = threadIdx.x;
    const int lane = tid & 63, w = tid >> 6;
    const int lm = lane & 15, q = lane >> 4;
    const int wm = w & 1, wn = w >> 1;
    const int x7 = lm & 7;
    const int sw0 = (q ^ x7) * 16;
    const int sw1 = ((4 + q) ^ x7) * 16;

    const __bf16* ga[4];
    const __bf16* gb[2];
#pragma unroll
    for (int j = 0; j < 4; j++) {
        int c = j * 256 + tid;
        int r = c >> 3;
        int ks = ((c & 7) ^ (r & 7)) * 8;
        ga[j] = act + (size_t)(base + m0 + r) * HDIM + ks;
    }
#pragma unroll
    for (int j = 0; j < 2; j++) {
        int c = j * 256 + tid;
        int r = c >> 3;
        int ks = ((c & 7) ^ (r & 7)) * 8;
        gb[j] = w2e + (size_t)(n0 + r) * HDIM + ks;
    }

    f32x4 acc[4][2];
#pragma unroll
    for (int mt = 0; mt < 4; mt++)
#pragma unroll
        for (int nt = 0; nt < 2; nt++) acc[mt][nt] = (f32x4){0.f, 0.f, 0.f, 0.f};

    for (int k0 = 0; k0 < HDIM; k0 += 64) {
        __syncthreads();
#pragma unroll
        for (int j = 0; j < 4; j++) {
            int c = j * 256 + tid;
            GLOAD_LDS16(ga[j], (char*)&As[0][0] + c * 16);
            ga[j] += 64;
        }
#pragma unroll
        for (int j = 0; j < 2; j++) {
            int c = j * 256 + tid;
            GLOAD_LDS16(gb[j], (char*)&Bs[0][0] + c * 16);
            gb[j] += 64;
        }
        __syncthreads();
#pragma unroll
        for (int kh = 0; kh < 2; kh++) {
            const int sw = kh ? sw1 : sw0;
            bf16x8 af[4];
#pragma unroll
            for (int mt = 0; mt < 4; mt++)
                af[mt] = *(const bf16x8*)((const char*)&As[wm * 64 + mt * 16 + lm][0] + sw);
#pragma unroll
            for (int nt = 0; nt < 2; nt++) {
                bf16x8 bfr = *(const bf16x8*)((const char*)&Bs[wn * 32 + nt * 16 + lm][0] + sw);
#pragma unroll
                for (int mt = 0; mt < 4; mt++)
                    acc[mt][nt] = __builtin_amdgcn_mfma_f32_16x16x32_bf16(af[mt], bfr, acc[mt][nt], 0, 0, 0);
            }
        }
    }

    // fused combine: out[tok] += p[pair] * acc  (out zeroed by prep)
    int pi[4][4];
    float pw[4][4];
#pragma unroll
    for (int mt = 0; mt < 4; mt++)
#pragma unroll
        for (int r = 0; r < 4; r++) {
            int gm = m0 + wm * 64 + mt * 16 + q * 4 + r;
            if (gm < cnt) {
                int pr = order[base + gm];
                pi[mt][r] = pr;
                pw[mt][r] = p[pr];
            } else pi[mt][r] = -1;
        }
#pragma unroll
    for (int mt = 0; mt < 4; mt++)
#pragma unroll
        for (int nt = 0; nt < 2; nt++) {
            int col = n0 + wn * 32 + nt * 16 + lm;
#pragma unroll
            for (int r = 0; r < 4; r++) {
                if (pi[mt][r] >= 0) {
                    int tok = pi[mt][r] >> 1;
                    atomicAdd(out + (size_t)tok * DDIM + col, pw[mt][r] * acc[mt][nt][r]);
                }
            }
        }
}

extern "C" void kernel_launch(void* const* d_in, const int* in_sizes, int n_in,
                              void* d_out, int out_size, void* d_ws, size_t ws_size,
                              hipStream_t stream) {
    (void)in_sizes; (void)n_in; (void)out_size; (void)ws_size;
    const float* x   = (const float*)d_in[0];
    const float* p   = (const float*)d_in[1];
    const int* eidx  = (const int*)d_in[2];
    const float* W1  = (const float*)d_in[3];
    const float* W2  = (const float*)d_in[4];
    float* out = (float*)d_out;

    char* ws = (char*)d_ws;
    int* wsi     = (int*)ws;
    __bf16* xb   = (__bf16*)(ws + XB_OFF);
    __bf16* w1t  = (__bf16*)(ws + W1T_OFF);
    __bf16* w2t  = (__bf16*)(ws + W2T_OFF);
    __bf16* act  = (__bf16*)(ws + ACT_OFF);

    prep_kernel<<<8705, 256, 0, stream>>>(x, W1, W2, eidx, wsi, xb, w1t, w2t, out);
    gemm1_kernel<<<dim3(16, 32, NEXP), 256, 0, stream>>>(xb, w1t, wsi, act);
    gemm2_kernel<<<dim3(16, 32, NEXP), 256, 0, stream>>>(act, w2t, wsi, p, out);
}

// Round 5
// 221.831 us; speedup vs baseline: 1.0617x; 1.0023x over previous
//
#include <hip/hip_runtime.h>

// MoE GLU MLP: E=8, D=1024, H=1024, K=2, N=2048 tokens, 4096 pairs.
// 3 kernels: prep (bucket(8 blk) + x->bf16 + W1^T/W2^T->bf16 16B-stores + zero out),
//            gemm1 (x@W1 + SiLU-GLU, BK=64, XOR-swizzled LDS)  [unchanged from R4],
//            gemm2 (act@W2, fused gate-weighted atomic combine) [unchanged from R4].

typedef __bf16 bf16x8 __attribute__((ext_vector_type(8)));
typedef __bf16 bf16x4 __attribute__((ext_vector_type(4)));
typedef float  f32x4  __attribute__((ext_vector_type(4)));

#define NPAIR 4096
#define NTOK  2048
#define DDIM  1024
#define HDIM  1024
#define NEXP  8

// workspace layout (bytes)
#define ORDER_I   64                      // int index of order[] in wsi
#define XB_OFF    (24576)                 // bf16 x        [2048][1024]   4 MB
#define W1T_OFF   (XB_OFF + 4194304)      // bf16 W1^T  [8][2048][1024]  32 MB
#define W2T_OFF   (W1T_OFF + 33554432)    // bf16 W2^T  [8][1024][1024]  16 MB
#define ACT_OFF   (W2T_OFF + 16777216)    // bf16 act      [5120][1024] 10.5 MB

#define GLOAD_LDS16(g, l) \
    __builtin_amdgcn_global_load_lds( \
        (const __attribute__((address_space(1))) void*)(g), \
        (__attribute__((address_space(3))) void*)(l), 16, 0, 0)

// ---------------- prep: one kernel, block-level job dispatch ----------------
// blocks [0,2048):      W1 transpose-convert tiles (128k x 64n)
// blocks [2048,3072):   W2 transpose-convert tiles (128k x 64n)
// blocks [3072,5120):   x -> bf16 chunks (1024 elems)
// blocks [5120,5632):   zero d_out chunks (4096 floats)
// blocks [5632,5640):   bucket, one block per expert (redundant counts, own scatter)
__device__ __forceinline__ void tcvt_tile2(const float* __restrict__ s,
                                           __bf16* __restrict__ d,
                                           int R, int C, int k0, int c0,
                                           float (*tt)[65], int tid) {
    // load: 128 src rows (k) x 64 cols (n), float4 per lane, conflict-free LDS writes
#pragma unroll
    for (int p = 0; p < 8; p++) {
        int kr = p * 16 + (tid >> 4);
        int nc = (tid & 15) * 4;
        float4 v = *(const float4*)(s + (size_t)(k0 + kr) * C + c0 + nc);
        *(float4*)&tt[kr][nc] = v;
    }
    __syncthreads();
    // store: chunk cid -> n = cid>>4, k-chunk kc = cid&15; one bf16x8 (16 B) per lane.
    // Wave covers 4 dst rows x 256 B contiguous segments.
#pragma unroll
    for (int p = 0; p < 4; p++) {
        int cid = p * 256 + tid;
        int n = cid >> 4, kc = cid & 15;
        bf16x8 o;
#pragma unroll
        for (int j = 0; j < 8; j++) o[j] = (__bf16)tt[kc * 8 + j][n];
        *(bf16x8*)(d + (size_t)(c0 + n) * R + k0 + kc * 8) = o;
    }
}

__global__ __launch_bounds__(256) void prep_kernel(const float* __restrict__ x,
                                                   const float* __restrict__ W1,
                                                   const float* __restrict__ W2,
                                                   const int* __restrict__ idx,
                                                   int* __restrict__ wsi,
                                                   __bf16* __restrict__ xb,
                                                   __bf16* __restrict__ w1t,
                                                   __bf16* __restrict__ w2t,
                                                   float* __restrict__ out) {
    __shared__ float tt[128][65];
    __shared__ int cnt[NEXP];
    __shared__ int sbase, scur;
    const int b = blockIdx.x;
    const int tid = threadIdx.x;
    if (b < 2048) {
        // W1: R=1024 (k=D), C=2048 (n); 256 tiles/expert = 8 k-tiles x 32 n-tiles
        int e = b >> 8, t2 = b & 255;
        int k0 = (t2 & 7) * 128, c0 = (t2 >> 3) * 64;
        tcvt_tile2(W1 + (size_t)e * DDIM * 2 * HDIM, w1t + (size_t)e * 2 * HDIM * DDIM,
                   DDIM, 2 * HDIM, k0, c0, tt, tid);
    } else if (b < 3072) {
        // W2: R=1024 (k=H), C=1024 (n); 128 tiles/expert
        int b2 = b - 2048;
        int e = b2 >> 7, t2 = b2 & 127;
        int k0 = (t2 & 7) * 128, c0 = (t2 >> 3) * 64;
        tcvt_tile2(W2 + (size_t)e * HDIM * DDIM, w2t + (size_t)e * DDIM * HDIM,
                   HDIM, DDIM, k0, c0, tt, tid);
    } else if (b < 5120) {
        int i = (b - 3072) * 1024 + tid * 4;
        float4 v = *(const float4*)(x + i);
        bf16x4 o;
        o[0] = (__bf16)v.x; o[1] = (__bf16)v.y; o[2] = (__bf16)v.z; o[3] = (__bf16)v.w;
        *(bf16x4*)(xb + i) = o;
    } else if (b < 5632) {
        int base4 = (b - 5120) * 4096;
        float4 z = {0.f, 0.f, 0.f, 0.f};
#pragma unroll
        for (int j = 0; j < 4; j++)
            *(float4*)(out + base4 + j * 1024 + tid * 4) = z;
    } else {
        // bucket: block handles expert e; counts all experts to derive own base
        const int e = b - 5632;
        if (tid < NEXP) cnt[tid] = 0;
        if (tid == 0) scur = 0;
        __syncthreads();
        for (int i = tid; i < NPAIR; i += 256) atomicAdd(&cnt[idx[i] & 7], 1);
        __syncthreads();
        if (tid == 0) {
            int off = 0;
            for (int e2 = 0; e2 < NEXP; e2++) {
                if (e2 == e) { wsi[e] = cnt[e]; wsi[8 + e] = off; sbase = off; }
                off += (cnt[e2] + 127) & ~127;
            }
        }
        __syncthreads();
        for (int i = tid; i < NPAIR; i += 256) {
            if ((idx[i] & 7) == e) {
                int s = atomicAdd(&scur, 1);
                wsi[ORDER_I + sbase + s] = i;
            }
        }
    }
}

// ---------------- gemm1: 128m x 64 out-cols, BK=64, swizzled LDS (unchanged R4)
__global__ __launch_bounds__(256) void gemm1_kernel(const __bf16* __restrict__ xb,
                                                    const __bf16* __restrict__ w1t,
                                                    const int* __restrict__ wsi,
                                                    __bf16* __restrict__ act) {
    const int e = blockIdx.z;
    const int cnt = wsi[e];
    const int m0 = blockIdx.y * 128;
    if (m0 >= cnt) return;
    const int base = wsi[8 + e];
    const int n0 = blockIdx.x * 64;
    const int* order = wsi + ORDER_I;
    const __bf16* w1e = w1t + (size_t)e * 2048 * 1024;

    __shared__ __align__(16) __bf16 As[128][64];
    __shared__ __align__(16) __bf16 Bs[128][64];

    const int tid = threadIdx.x;
    const int lane = tid & 63, w = tid >> 6;
    const int lm = lane & 15, q = lane >> 4;
    const int wm = w & 1, wn = w >> 1;
    const int x7 = lm & 7;
    const int sw0 = (q ^ x7) * 16;
    const int sw1 = ((4 + q) ^ x7) * 16;

    const __bf16* ga[4];
    const __bf16* gb[4];
#pragma unroll
    for (int j = 0; j < 4; j++) {
        int c = j * 256 + tid;
        int r = c >> 3;
        int ks = ((c & 7) ^ (r & 7)) * 8;
        int m = m0 + r; if (m >= cnt) m = cnt - 1;
        int tok = order[base + m] >> 1;
        ga[j] = xb + (size_t)tok * DDIM + ks;
        int half = r >> 6, rr = r & 63;
        int rb = (rr < 32) ? (n0 + half * 32 + rr)
                           : (HDIM + n0 + half * 32 + (rr - 32));
        gb[j] = w1e + (size_t)rb * DDIM + ks;
    }

    f32x4 acc[4][4];
#pragma unroll
    for (int mt = 0; mt < 4; mt++)
#pragma unroll
        for (int nt = 0; nt < 4; nt++) acc[mt][nt] = (f32x4){0.f, 0.f, 0.f, 0.f};

    for (int k0 = 0; k0 < DDIM; k0 += 64) {
        __syncthreads();
#pragma unroll
        for (int j = 0; j < 4; j++) {
            int c = j * 256 + tid;
            GLOAD_LDS16(ga[j], (char*)&As[0][0] + c * 16);
            GLOAD_LDS16(gb[j], (char*)&Bs[0][0] + c * 16);
            ga[j] += 64; gb[j] += 64;
        }
        __syncthreads();
#pragma unroll
        for (int kh = 0; kh < 2; kh++) {
            const int sw = kh ? sw1 : sw0;
            bf16x8 af[4];
#pragma unroll
            for (int mt = 0; mt < 4; mt++)
                af[mt] = *(const bf16x8*)((const char*)&As[wm * 64 + mt * 16 + lm][0] + sw);
#pragma unroll
            for (int nt = 0; nt < 4; nt++) {
                bf16x8 bfr = *(const bf16x8*)((const char*)&Bs[wn * 64 + nt * 16 + lm][0] + sw);
#pragma unroll
                for (int mt = 0; mt < 4; mt++)
                    acc[mt][nt] = __builtin_amdgcn_mfma_f32_16x16x32_bf16(af[mt], bfr, acc[mt][nt], 0, 0, 0);
            }
        }
    }

#pragma unroll
    for (int mt = 0; mt < 4; mt++) {
        int mbase = m0 + wm * 64 + mt * 16 + q * 4;
#pragma unroll
        for (int ntp = 0; ntp < 2; ntp++) {
            int col = n0 + wn * 32 + ntp * 16 + lm;
#pragma unroll
            for (int r = 0; r < 4; r++) {
                int m = mbase + r;
                if (m < cnt) {
                    float h = acc[mt][ntp][r];
                    float g = acc[mt][ntp + 2][r];
                    float a = h * (g / (1.f + __expf(-g)));
                    act[(size_t)(base + m) * HDIM + col] = (__bf16)a;
                }
            }
        }
    }
}

// ---------------- gemm2: 128m x 64n, BK=64, fused atomic combine (unchanged R4)
__global__ __launch_bounds__(256) void gemm2_kernel(const __bf16* __restrict__ act,
                                                    const __bf16* __restrict__ w2t,
                                                    const int* __restrict__ wsi,
                                                    const float* __restrict__ p,
                                                    float* __restrict__ out) {
    const int e = blockIdx.z;
    const int cnt = wsi[e];
    const int m0 = blockIdx.y * 128;
    if (m0 >= cnt) return;
    const int base = wsi[8 + e];
    const int n0 = blockIdx.x * 64;
    const int* order = wsi + ORDER_I;
    const __bf16* w2e = w2t + (size_t)e * 1024 * 1024;

    __shared__ __align__(16) __bf16 As[128][64];
    __shared__ __align__(16) __bf16 Bs[64][64];

    const int tid = threadIdx.x;
    const int lane = tid & 63, w = tid >> 6;
    const int lm = lane & 15, q = lane >> 4;
    const int wm = w & 1, wn = w >> 1;
    const int x7 = lm & 7;
    const int sw0 = (q ^ x7) * 16;
    const int sw1 = ((4 + q) ^ x7) * 16;

    const __bf16* ga[4];
    const __bf16* gb[2];
#pragma unroll
    for (int j = 0; j < 4; j++) {
        int c = j * 256 + tid;
        int r = c >> 3;
        int ks = ((c & 7) ^ (r & 7)) * 8;
        ga[j] = act + (size_t)(base + m0 + r) * HDIM + ks;
    }
#pragma unroll
    for (int j = 0; j < 2; j++) {
        int c = j * 256 + tid;
        int r = c >> 3;
        int ks = ((c & 7) ^ (r & 7)) * 8;
        gb[j] = w2e + (size_t)(n0 + r) * HDIM + ks;
    }

    f32x4 acc[4][2];
#pragma unroll
    for (int mt = 0; mt < 4; mt++)
#pragma unroll
        for (int nt = 0; nt < 2; nt++) acc[mt][nt] = (f32x4){0.f, 0.f, 0.f, 0.f};

    for (int k0 = 0; k0 < HDIM; k0 += 64) {
        __syncthreads();
#pragma unroll
        for (int j = 0; j < 4; j++) {
            int c = j * 256 + tid;
            GLOAD_LDS16(ga[j], (char*)&As[0][0] + c * 16);
            ga[j] += 64;
        }
#pragma unroll
        for (int j = 0; j < 2; j++) {
            int c = j * 256 + tid;
            GLOAD_LDS16(gb[j], (char*)&Bs[0][0] + c * 16);
            gb[j] += 64;
        }
        __syncthreads();
#pragma unroll
        for (int kh = 0; kh < 2; kh++) {
            const int sw = kh ? sw1 : sw0;
            bf16x8 af[4];
#pragma unroll
            for (int mt = 0; mt < 4; mt++)
                af[mt] = *(const bf16x8*)((const char*)&As[wm * 64 + mt * 16 + lm][0] + sw);
#pragma unroll
            for (int nt = 0; nt < 2; nt++) {
                bf16x8 bfr = *(const bf16x8*)((const char*)&Bs[wn * 32 + nt * 16 + lm][0] + sw);
#pragma unroll
                for (int mt = 0; mt < 4; mt++)
                    acc[mt][nt] = __builtin_amdgcn_mfma_f32_16x16x32_bf16(af[mt], bfr, acc[mt][nt], 0, 0, 0);
            }
        }
    }

    int pi[4][4];
    float pw[4][4];
#pragma unroll
    for (int mt = 0; mt < 4; mt++)
#pragma unroll
        for (int r = 0; r < 4; r++) {
            int gm = m0 + wm * 64 + mt * 16 + q * 4 + r;
            if (gm < cnt) {
                int pr = order[base + gm];
                pi[mt][r] = pr;
                pw[mt][r] = p[pr];
            } else pi[mt][r] = -1;
        }
#pragma unroll
    for (int mt = 0; mt < 4; mt++)
#pragma unroll
        for (int nt = 0; nt < 2; nt++) {
            int col = n0 + wn * 32 + nt * 16 + lm;
#pragma unroll
            for (int r = 0; r < 4; r++) {
                if (pi[mt][r] >= 0) {
                    int tok = pi[mt][r] >> 1;
                    atomicAdd(out + (size_t)tok * DDIM + col, pw[mt][r] * acc[mt][nt][r]);
                }
            }
        }
}

extern "C" void kernel_launch(void* const* d_in, const int* in_sizes, int n_in,
                              void* d_out, int out_size, void* d_ws, size_t ws_size,
                              hipStream_t stream) {
    (void)in_sizes; (void)n_in; (void)out_size; (void)ws_size;
    const float* x   = (const float*)d_in[0];
    const float* p   = (const float*)d_in[1];
    const int* eidx  = (const int*)d_in[2];
    const float* W1  = (const float*)d_in[3];
    const float* W2  = (const float*)d_in[4];
    float* out = (float*)d_out;

    char* ws = (char*)d_ws;
    int* wsi     = (int*)ws;
    __bf16* xb   = (__bf16*)(ws + XB_OFF);
    __bf16* w1t  = (__bf16*)(ws + W1T_OFF);
    __bf16* w2t  = (__bf16*)(ws + W2T_OFF);
    __bf16* act  = (__bf16*)(ws + ACT_OFF);

    prep_kernel<<<5640, 256, 0, stream>>>(x, W1, W2, eidx, wsi, xb, w1t, w2t, out);
    gemm1_kernel<<<dim3(16, 32, NEXP), 256, 0, stream>>>(xb, w1t, wsi, act);
    gemm2_kernel<<<dim3(16, 32, NEXP), 256, 0, stream>>>(act, w2t, wsi, p, out);
}

// Round 6
// 216.601 us; speedup vs baseline: 1.0873x; 1.0241x over previous
//
#include <hip/hip_runtime.h>

// MoE GLU MLP: E=8, D=1024, H=1024, K=2, N=2048 tokens, 4096 pairs.
// prep:  bucket(8 blk) + x->bf16 + W1^T->bf16 only   (critical path for gemm1)
// gemm1: x@W1 + SiLU-GLU (z<8)  ++  aux slices (z>=8): W2^T-cvt + out-zero,
//        overlapped with gemm1 compute; kernel boundary orders them before gemm2.
// gemm2: act@W2, fused gate-weighted atomic combine into out.  [core frozen since R4]

typedef __bf16 bf16x8 __attribute__((ext_vector_type(8)));
typedef __bf16 bf16x4 __attribute__((ext_vector_type(4)));
typedef float  f32x4  __attribute__((ext_vector_type(4)));

#define NPAIR 4096
#define NTOK  2048
#define DDIM  1024
#define HDIM  1024
#define NEXP  8

// workspace layout (bytes)
#define ORDER_I   64                      // int index of order[] in wsi
#define XB_OFF    (24576)                 // bf16 x        [2048][1024]   4 MB
#define W1T_OFF   (XB_OFF + 4194304)      // bf16 W1^T  [8][2048][1024]  32 MB
#define W2T_OFF   (W1T_OFF + 33554432)    // bf16 W2^T  [8][1024][1024]  16 MB
#define ACT_OFF   (W2T_OFF + 16777216)    // bf16 act      [5120][1024] 10.5 MB

#define GLOAD_LDS16(g, l) \
    __builtin_amdgcn_global_load_lds( \
        (const __attribute__((address_space(1))) void*)(g), \
        (__attribute__((address_space(3))) void*)(l), 16, 0, 0)

// 64k x 64n transpose-convert tile: fp32 LDS bounce, float4 loads, bf16x8 (16B) stores
__device__ __forceinline__ void tcvt64(const float* __restrict__ s,
                                       __bf16* __restrict__ d,
                                       int R, int C, int k0, int c0,
                                       float (*tt)[65], int tid) {
#pragma unroll
    for (int p = 0; p < 4; p++) {
        int kr = p * 16 + (tid >> 4);
        int nc = (tid & 15) * 4;
        *(float4*)&tt[kr][nc] = *(const float4*)(s + (size_t)(k0 + kr) * C + c0 + nc);
    }
    __syncthreads();
#pragma unroll
    for (int p = 0; p < 2; p++) {
        int cid = p * 256 + tid;
        int n = cid >> 3, kc = cid & 7;
        bf16x8 o;
#pragma unroll
        for (int j = 0; j < 8; j++) o[j] = (__bf16)tt[kc * 8 + j][n];
        *(bf16x8*)(d + (size_t)(c0 + n) * R + k0 + kc * 8) = o;
    }
}

// ---------------- prep: W1-cvt (4096) + x-cvt (2048) + bucket (8) ----------------
__global__ __launch_bounds__(256) void prep_kernel(const float* __restrict__ x,
                                                   const float* __restrict__ W1,
                                                   const int* __restrict__ idx,
                                                   int* __restrict__ wsi,
                                                   __bf16* __restrict__ xb,
                                                   __bf16* __restrict__ w1t) {
    __shared__ float tt[64][65];
    __shared__ int cnt[NEXP];
    __shared__ int sbase, scur;
    const int b = blockIdx.x;
    const int tid = threadIdx.x;
    if (b < 4096) {
        // W1: k=D rows (R=1024), n=2H cols (C=2048); 512 tiles/expert = 16k x 32n
        int e = b >> 9, t2 = b & 511;
        int k0 = (t2 & 15) * 64, c0 = (t2 >> 4) * 64;
        tcvt64(W1 + (size_t)e * DDIM * 2 * HDIM, w1t + (size_t)e * 2 * HDIM * DDIM,
               DDIM, 2 * HDIM, k0, c0, tt, tid);
    } else if (b < 6144) {
        int i = (b - 4096) * 1024 + tid * 4;
        float4 v = *(const float4*)(x + i);
        bf16x4 o;
        o[0] = (__bf16)v.x; o[1] = (__bf16)v.y; o[2] = (__bf16)v.z; o[3] = (__bf16)v.w;
        *(bf16x4*)(xb + i) = o;
    } else {
        // bucket: block handles expert e; counts all experts to derive own base
        const int e = b - 6144;
        if (tid < NEXP) cnt[tid] = 0;
        if (tid == 0) scur = 0;
        __syncthreads();
        for (int i = tid; i < NPAIR; i += 256) atomicAdd(&cnt[idx[i] & 7], 1);
        __syncthreads();
        if (tid == 0) {
            int off = 0;
            for (int e2 = 0; e2 < NEXP; e2++) {
                if (e2 == e) { wsi[e] = cnt[e]; wsi[8 + e] = off; sbase = off; }
                off += (cnt[e2] + 127) & ~127;
            }
        }
        __syncthreads();
        for (int i = tid; i < NPAIR; i += 256) {
            if ((idx[i] & 7) == e) {
                int s = atomicAdd(&scur, 1);
                wsi[ORDER_I + sbase + s] = i;
            }
        }
    }
}

// ---------------- gemm1 (z<8) + aux W2-cvt / out-zero (z>=8) ----------------
__global__ __launch_bounds__(256) void gemm1_kernel(const __bf16* __restrict__ xb,
                                                    const __bf16* __restrict__ w1t,
                                                    const int* __restrict__ wsi,
                                                    __bf16* __restrict__ act,
                                                    const float* __restrict__ W2,
                                                    __bf16* __restrict__ w2t,
                                                    float* __restrict__ out) {
    __shared__ __align__(16) char smem[32768];   // GEMM: As|Bs; aux: fp32 [64][65] tile
    const int tid = threadIdx.x;
    const int z = blockIdx.z;

    if (z >= 8) {
        int aux = (z - 8) * 512 + blockIdx.y * 16 + blockIdx.x;
        if (aux < 2048) {
            // W2: k=H rows (R=1024), n=D cols (C=1024); 256 tiles/expert = 16k x 16n
            int e = aux >> 8, t2 = aux & 255;
            int k0 = (t2 & 15) * 64, c0 = (t2 >> 4) * 64;
            tcvt64(W2 + (size_t)e * HDIM * DDIM, w2t + (size_t)e * DDIM * HDIM,
                   HDIM, DDIM, k0, c0, (float (*)[65])smem, tid);
        } else {
            int zb = aux - 2048;                 // 512 blocks zero 8 MB
            float4 z4 = {0.f, 0.f, 0.f, 0.f};
            int b4 = zb * 4096;
#pragma unroll
            for (int j = 0; j < 4; j++)
                *(float4*)(out + b4 + j * 1024 + tid * 4) = z4;
        }
        return;
    }

    const int e = z;
    const int cnt = wsi[e];
    const int m0 = blockIdx.y * 128;
    if (m0 >= cnt) return;
    const int base = wsi[8 + e];
    const int n0 = blockIdx.x * 64;
    const int* order = wsi + ORDER_I;
    const __bf16* w1e = w1t + (size_t)e * 2048 * 1024;

    __bf16 (*As)[64] = (__bf16 (*)[64])smem;
    __bf16 (*Bs)[64] = (__bf16 (*)[64])(smem + 16384);

    const int lane = tid & 63, w = tid >> 6;
    const int lm = lane & 15, q = lane >> 4;
    const int wm = w & 1, wn = w >> 1;
    const int x7 = lm & 7;
    const int sw0 = (q ^ x7) * 16;
    const int sw1 = ((4 + q) ^ x7) * 16;

    const __bf16* ga[4];
    const __bf16* gb[4];
#pragma unroll
    for (int j = 0; j < 4; j++) {
        int c = j * 256 + tid;
        int r = c >> 3;
        int ks = ((c & 7) ^ (r & 7)) * 8;
        int m = m0 + r; if (m >= cnt) m = cnt - 1;
        int tok = order[base + m] >> 1;
        ga[j] = xb + (size_t)tok * DDIM + ks;
        int half = r >> 6, rr = r & 63;
        int rb = (rr < 32) ? (n0 + half * 32 + rr)
                           : (HDIM + n0 + half * 32 + (rr - 32));
        gb[j] = w1e + (size_t)rb * DDIM + ks;
    }

    f32x4 acc[4][4];
#pragma unroll
    for (int mt = 0; mt < 4; mt++)
#pragma unroll
        for (int nt = 0; nt < 4; nt++) acc[mt][nt] = (f32x4){0.f, 0.f, 0.f, 0.f};

    for (int k0 = 0; k0 < DDIM; k0 += 64) {
        __syncthreads();
#pragma unroll
        for (int j = 0; j < 4; j++) {
            int c = j * 256 + tid;
            GLOAD_LDS16(ga[j], (char*)&As[0][0] + c * 16);
            GLOAD_LDS16(gb[j], (char*)&Bs[0][0] + c * 16);
            ga[j] += 64; gb[j] += 64;
        }
        __syncthreads();
#pragma unroll
        for (int kh = 0; kh < 2; kh++) {
            const int sw = kh ? sw1 : sw0;
            bf16x8 af[4];
#pragma unroll
            for (int mt = 0; mt < 4; mt++)
                af[mt] = *(const bf16x8*)((const char*)&As[wm * 64 + mt * 16 + lm][0] + sw);
#pragma unroll
            for (int nt = 0; nt < 4; nt++) {
                bf16x8 bfr = *(const bf16x8*)((const char*)&Bs[wn * 64 + nt * 16 + lm][0] + sw);
#pragma unroll
                for (int mt = 0; mt < 4; mt++)
                    acc[mt][nt] = __builtin_amdgcn_mfma_f32_16x16x32_bf16(af[mt], bfr, acc[mt][nt], 0, 0, 0);
            }
        }
    }

#pragma unroll
    for (int mt = 0; mt < 4; mt++) {
        int mbase = m0 + wm * 64 + mt * 16 + q * 4;
#pragma unroll
        for (int ntp = 0; ntp < 2; ntp++) {
            int col = n0 + wn * 32 + ntp * 16 + lm;
#pragma unroll
            for (int r = 0; r < 4; r++) {
                int m = mbase + r;
                if (m < cnt) {
                    float h = acc[mt][ntp][r];
                    float g = acc[mt][ntp + 2][r];
                    float a = h * (g / (1.f + __expf(-g)));
                    act[(size_t)(base + m) * HDIM + col] = (__bf16)a;
                }
            }
        }
    }
}

// ---------------- gemm2: 128m x 64n, BK=64, fused atomic combine (frozen) ----------------
__global__ __launch_bounds__(256) void gemm2_kernel(const __bf16* __restrict__ act,
                                                    const __bf16* __restrict__ w2t,
                                                    const int* __restrict__ wsi,
                                                    const float* __restrict__ p,
                                                    float* __restrict__ out) {
    const int e = blockIdx.z;
    const int cnt = wsi[e];
    const int m0 = blockIdx.y * 128;
    if (m0 >= cnt) return;
    const int base = wsi[8 + e];
    const int n0 = blockIdx.x * 64;
    const int* order = wsi + ORDER_I;
    const __bf16* w2e = w2t + (size_t)e * 1024 * 1024;

    __shared__ __align__(16) __bf16 As[128][64];
    __shared__ __align__(16) __bf16 Bs[64][64];

    const int tid = threadIdx.x;
    const int lane = tid & 63, w = tid >> 6;
    const int lm = lane & 15, q = lane >> 4;
    const int wm = w & 1, wn = w >> 1;
    const int x7 = lm & 7;
    const int sw0 = (q ^ x7) * 16;
    const int sw1 = ((4 + q) ^ x7) * 16;

    const __bf16* ga[4];
    const __bf16* gb[2];
#pragma unroll
    for (int j = 0; j < 4; j++) {
        int c = j * 256 + tid;
        int r = c >> 3;
        int ks = ((c & 7) ^ (r & 7)) * 8;
        ga[j] = act + (size_t)(base + m0 + r) * HDIM + ks;
    }
#pragma unroll
    for (int j = 0; j < 2; j++) {
        int c = j * 256 + tid;
        int r = c >> 3;
        int ks = ((c & 7) ^ (r & 7)) * 8;
        gb[j] = w2e + (size_t)(n0 + r) * HDIM + ks;
    }

    f32x4 acc[4][2];
#pragma unroll
    for (int mt = 0; mt < 4; mt++)
#pragma unroll
        for (int nt = 0; nt < 2; nt++) acc[mt][nt] = (f32x4){0.f, 0.f, 0.f, 0.f};

    for (int k0 = 0; k0 < HDIM; k0 += 64) {
        __syncthreads();
#pragma unroll
        for (int j = 0; j < 4; j++) {
            int c = j * 256 + tid;
            GLOAD_LDS16(ga[j], (char*)&As[0][0] + c * 16);
            ga[j] += 64;
        }
#pragma unroll
        for (int j = 0; j < 2; j++) {
            int c = j * 256 + tid;
            GLOAD_LDS16(gb[j], (char*)&Bs[0][0] + c * 16);
            gb[j] += 64;
        }
        __syncthreads();
#pragma unroll
        for (int kh = 0; kh < 2; kh++) {
            const int sw = kh ? sw1 : sw0;
            bf16x8 af[4];
#pragma unroll
            for (int mt = 0; mt < 4; mt++)
                af[mt] = *(const bf16x8*)((const char*)&As[wm * 64 + mt * 16 + lm][0] + sw);
#pragma unroll
            for (int nt = 0; nt < 2; nt++) {
                bf16x8 bfr = *(const bf16x8*)((const char*)&Bs[wn * 32 + nt * 16 + lm][0] + sw);
#pragma unroll
                for (int mt = 0; mt < 4; mt++)
                    acc[mt][nt] = __builtin_amdgcn_mfma_f32_16x16x32_bf16(af[mt], bfr, acc[mt][nt], 0, 0, 0);
            }
        }
    }

    int pi[4][4];
    float pw[4][4];
#pragma unroll
    for (int mt = 0; mt < 4; mt++)
#pragma unroll
        for (int r = 0; r < 4; r++) {
            int gm = m0 + wm * 64 + mt * 16 + q * 4 + r;
            if (gm < cnt) {
                int pr = order[base + gm];
                pi[mt][r] = pr;
                pw[mt][r] = p[pr];
            } else pi[mt][r] = -1;
        }
#pragma unroll
    for (int mt = 0; mt < 4; mt++)
#pragma unroll
        for (int nt = 0; nt < 2; nt++) {
            int col = n0 + wn * 32 + nt * 16 + lm;
#pragma unroll
            for (int r = 0; r < 4; r++) {
                if (pi[mt][r] >= 0) {
                    int tok = pi[mt][r] >> 1;
                    atomicAdd(out + (size_t)tok * DDIM + col, pw[mt][r] * acc[mt][nt][r]);
                }
            }
        }
}

extern "C" void kernel_launch(void* const* d_in, const int* in_sizes, int n_in,
                              void* d_out, int out_size, void* d_ws, size_t ws_size,
                              hipStream_t stream) {
    (void)in_sizes; (void)n_in; (void)out_size; (void)ws_size;
    const float* x   = (const float*)d_in[0];
    const float* p   = (const float*)d_in[1];
    const int* eidx  = (const int*)d_in[2];
    const float* W1  = (const float*)d_in[3];
    const float* W2  = (const float*)d_in[4];
    float* out = (float*)d_out;

    char* ws = (char*)d_ws;
    int* wsi     = (int*)ws;
    __bf16* xb   = (__bf16*)(ws + XB_OFF);
    __bf16* w1t  = (__bf16*)(ws + W1T_OFF);
    __bf16* w2t  = (__bf16*)(ws + W2T_OFF);
    __bf16* act  = (__bf16*)(ws + ACT_OFF);

    prep_kernel<<<6152, 256, 0, stream>>>(x, W1, eidx, wsi, xb, w1t);
    // z<8: gemm1; z in [8,13): 2048 W2-cvt tiles + 512 out-zero blocks (ride-along)
    gemm1_kernel<<<dim3(16, 32, 13), 256, 0, stream>>>(xb, w1t, wsi, act, W2, w2t, out);
    gemm2_kernel<<<dim3(16, 32, NEXP), 256, 0, stream>>>(act, w2t, wsi, p, out);
}

// Round 7
// 202.656 us; speedup vs baseline: 1.1621x; 1.0688x over previous
//
#include <hip/hip_runtime.h>

// MoE GLU MLP: E=8, D=1024, H=1024, K=2, N=2048 tokens, 4096 pairs.
// prep:  bucket(8 blk) + x->bf16 + W1^T->bf16  (critical path for gemm1)
// gemm1: x@W1 + SiLU-GLU, 64m x 64out-cols tiles (z<8) ++ aux (z>=8): W2^T-cvt + out-zero
// gemm2: act@W2, 64m x 64n tiles, fused gate-weighted atomic combine into out.
// R7 change: m-tile 128->64 in both GEMMs (~4.3 live blocks/CU vs 2.25) to hide
// the vmcnt(0)+barrier staging latency via inter-block overlap (m114 mechanism).

typedef __bf16 bf16x8 __attribute__((ext_vector_type(8)));
typedef __bf16 bf16x4 __attribute__((ext_vector_type(4)));
typedef float  f32x4  __attribute__((ext_vector_type(4)));

#define NPAIR 4096
#define NTOK  2048
#define DDIM  1024
#define HDIM  1024
#define NEXP  8

// workspace layout (bytes)
#define ORDER_I   64                      // int index of order[] in wsi
#define XB_OFF    (24576)                 // bf16 x        [2048][1024]   4 MB
#define W1T_OFF   (XB_OFF + 4194304)      // bf16 W1^T  [8][2048][1024]  32 MB
#define W2T_OFF   (W1T_OFF + 33554432)    // bf16 W2^T  [8][1024][1024]  16 MB
#define ACT_OFF   (W2T_OFF + 16777216)    // bf16 act      [5120][1024] 10.5 MB

#define GLOAD_LDS16(g, l) \
    __builtin_amdgcn_global_load_lds( \
        (const __attribute__((address_space(1))) void*)(g), \
        (__attribute__((address_space(3))) void*)(l), 16, 0, 0)

// 64k x 64n transpose-convert tile: fp32 LDS bounce, float4 loads, bf16x8 (16B) stores
__device__ __forceinline__ void tcvt64(const float* __restrict__ s,
                                       __bf16* __restrict__ d,
                                       int R, int C, int k0, int c0,
                                       float (*tt)[65], int tid) {
#pragma unroll
    for (int p = 0; p < 4; p++) {
        int kr = p * 16 + (tid >> 4);
        int nc = (tid & 15) * 4;
        *(float4*)&tt[kr][nc] = *(const float4*)(s + (size_t)(k0 + kr) * C + c0 + nc);
    }
    __syncthreads();
#pragma unroll
    for (int p = 0; p < 2; p++) {
        int cid = p * 256 + tid;
        int n = cid >> 3, kc = cid & 7;
        bf16x8 o;
#pragma unroll
        for (int j = 0; j < 8; j++) o[j] = (__bf16)tt[kc * 8 + j][n];
        *(bf16x8*)(d + (size_t)(c0 + n) * R + k0 + kc * 8) = o;
    }
}

// ---------------- prep: W1-cvt (4096) + x-cvt (2048) + bucket (8) ----------------
__global__ __launch_bounds__(256) void prep_kernel(const float* __restrict__ x,
                                                   const float* __restrict__ W1,
                                                   const int* __restrict__ idx,
                                                   int* __restrict__ wsi,
                                                   __bf16* __restrict__ xb,
                                                   __bf16* __restrict__ w1t) {
    __shared__ float tt[64][65];
    __shared__ int cnt[NEXP];
    __shared__ int sbase, scur;
    const int b = blockIdx.x;
    const int tid = threadIdx.x;
    if (b < 4096) {
        int e = b >> 9, t2 = b & 511;
        int k0 = (t2 & 15) * 64, c0 = (t2 >> 4) * 64;
        tcvt64(W1 + (size_t)e * DDIM * 2 * HDIM, w1t + (size_t)e * 2 * HDIM * DDIM,
               DDIM, 2 * HDIM, k0, c0, tt, tid);
    } else if (b < 6144) {
        int i = (b - 4096) * 1024 + tid * 4;
        float4 v = *(const float4*)(x + i);
        bf16x4 o;
        o[0] = (__bf16)v.x; o[1] = (__bf16)v.y; o[2] = (__bf16)v.z; o[3] = (__bf16)v.w;
        *(bf16x4*)(xb + i) = o;
    } else {
        const int e = b - 6144;
        if (tid < NEXP) cnt[tid] = 0;
        if (tid == 0) scur = 0;
        __syncthreads();
        for (int i = tid; i < NPAIR; i += 256) atomicAdd(&cnt[idx[i] & 7], 1);
        __syncthreads();
        if (tid == 0) {
            int off = 0;
            for (int e2 = 0; e2 < NEXP; e2++) {
                if (e2 == e) { wsi[e] = cnt[e]; wsi[8 + e] = off; sbase = off; }
                off += (cnt[e2] + 127) & ~127;
            }
        }
        __syncthreads();
        for (int i = tid; i < NPAIR; i += 256) {
            if ((idx[i] & 7) == e) {
                int s = atomicAdd(&scur, 1);
                wsi[ORDER_I + sbase + s] = i;
            }
        }
    }
}

// ---------------- gemm1: 64m x 64 out-cols (z<8) + aux (z>=8) ----------------
__global__ __launch_bounds__(256) void gemm1_kernel(const __bf16* __restrict__ xb,
                                                    const __bf16* __restrict__ w1t,
                                                    const int* __restrict__ wsi,
                                                    __bf16* __restrict__ act,
                                                    const float* __restrict__ W2,
                                                    __bf16* __restrict__ w2t,
                                                    float* __restrict__ out) {
    __shared__ __align__(16) char smem[24576];   // GEMM: As(8K)|Bs(16K); aux: fp32 [64][65]
    const int tid = threadIdx.x;
    const int z = blockIdx.z;

    if (z >= 8) {
        int aux = (z - 8) * 1024 + blockIdx.y * 16 + blockIdx.x;
        if (aux < 2048) {
            int e = aux >> 8, t2 = aux & 255;
            int k0 = (t2 & 15) * 64, c0 = (t2 >> 4) * 64;
            tcvt64(W2 + (size_t)e * HDIM * DDIM, w2t + (size_t)e * DDIM * HDIM,
                   HDIM, DDIM, k0, c0, (float (*)[65])smem, tid);
        } else if (aux < 2560) {
            int zb = aux - 2048;                 // 512 blocks zero 8 MB
            float4 z4 = {0.f, 0.f, 0.f, 0.f};
            int b4 = zb * 4096;
#pragma unroll
            for (int j = 0; j < 4; j++)
                *(float4*)(out + b4 + j * 1024 + tid * 4) = z4;
        }
        return;
    }

    const int e = z;
    const int cnt = wsi[e];
    const int m0 = blockIdx.y * 64;
    if (m0 >= cnt) return;
    const int base = wsi[8 + e];
    const int n0 = blockIdx.x * 64;
    const int* order = wsi + ORDER_I;
    const __bf16* w1e = w1t + (size_t)e * 2048 * 1024;

    __bf16 (*As)[64] = (__bf16 (*)[64])smem;             // [64][64]
    __bf16 (*Bs)[64] = (__bf16 (*)[64])(smem + 8192);    // [128][64] h+g interleaved

    const int lane = tid & 63, w = tid >> 6;
    const int lm = lane & 15, q = lane >> 4;
    const int wm = w & 1, wn = w >> 1;
    const int x7 = lm & 7;
    const int sw0 = (q ^ x7) * 16;
    const int sw1 = ((4 + q) ^ x7) * 16;

    const __bf16* ga[2];
    const __bf16* gb[4];
#pragma unroll
    for (int j = 0; j < 2; j++) {
        int c = j * 256 + tid;
        int r = c >> 3;
        int ks = ((c & 7) ^ (r & 7)) * 8;
        int m = m0 + r; if (m >= cnt) m = cnt - 1;
        int tok = order[base + m] >> 1;
        ga[j] = xb + (size_t)tok * DDIM + ks;
    }
#pragma unroll
    for (int j = 0; j < 4; j++) {
        int c = j * 256 + tid;
        int r = c >> 3;
        int ks = ((c & 7) ^ (r & 7)) * 8;
        int half = r >> 6, rr = r & 63;
        int rb = (rr < 32) ? (n0 + half * 32 + rr)
                           : (HDIM + n0 + half * 32 + (rr - 32));
        gb[j] = w1e + (size_t)rb * DDIM + ks;
    }

    f32x4 acc[2][4];
#pragma unroll
    for (int mt = 0; mt < 2; mt++)
#pragma unroll
        for (int nt = 0; nt < 4; nt++) acc[mt][nt] = (f32x4){0.f, 0.f, 0.f, 0.f};

    for (int k0 = 0; k0 < DDIM; k0 += 64) {
        __syncthreads();
#pragma unroll
        for (int j = 0; j < 2; j++) {
            int c = j * 256 + tid;
            GLOAD_LDS16(ga[j], (char*)&As[0][0] + c * 16);
            ga[j] += 64;
        }
#pragma unroll
        for (int j = 0; j < 4; j++) {
            int c = j * 256 + tid;
            GLOAD_LDS16(gb[j], (char*)&Bs[0][0] + c * 16);
            gb[j] += 64;
        }
        __syncthreads();
#pragma unroll
        for (int kh = 0; kh < 2; kh++) {
            const int sw = kh ? sw1 : sw0;
            bf16x8 af[2];
#pragma unroll
            for (int mt = 0; mt < 2; mt++)
                af[mt] = *(const bf16x8*)((const char*)&As[wm * 32 + mt * 16 + lm][0] + sw);
#pragma unroll
            for (int nt = 0; nt < 4; nt++) {
                bf16x8 bfr = *(const bf16x8*)((const char*)&Bs[wn * 64 + nt * 16 + lm][0] + sw);
#pragma unroll
                for (int mt = 0; mt < 2; mt++)
                    acc[mt][nt] = __builtin_amdgcn_mfma_f32_16x16x32_bf16(af[mt], bfr, acc[mt][nt], 0, 0, 0);
            }
        }
    }

#pragma unroll
    for (int mt = 0; mt < 2; mt++) {
        int mbase = m0 + wm * 32 + mt * 16 + q * 4;
#pragma unroll
        for (int ntp = 0; ntp < 2; ntp++) {
            int col = n0 + wn * 32 + ntp * 16 + lm;
#pragma unroll
            for (int r = 0; r < 4; r++) {
                int m = mbase + r;
                if (m < cnt) {
                    float h = acc[mt][ntp][r];
                    float g = acc[mt][ntp + 2][r];
                    float a = h * (g / (1.f + __expf(-g)));
                    act[(size_t)(base + m) * HDIM + col] = (__bf16)a;
                }
            }
        }
    }
}

// ---------------- gemm2: 64m x 64n, fused p-weighted atomic combine ----------------
__global__ __launch_bounds__(256) void gemm2_kernel(const __bf16* __restrict__ act,
                                                    const __bf16* __restrict__ w2t,
                                                    const int* __restrict__ wsi,
                                                    const float* __restrict__ p,
                                                    float* __restrict__ out) {
    const int e = blockIdx.z;
    const int cnt = wsi[e];
    const int m0 = blockIdx.y * 64;
    if (m0 >= cnt) return;
    const int base = wsi[8 + e];
    const int n0 = blockIdx.x * 64;
    const int* order = wsi + ORDER_I;
    const __bf16* w2e = w2t + (size_t)e * 1024 * 1024;

    __shared__ __align__(16) __bf16 As[64][64];
    __shared__ __align__(16) __bf16 Bs[64][64];

    const int tid = threadIdx.x;
    const int lane = tid & 63, w = tid >> 6;
    const int lm = lane & 15, q = lane >> 4;
    const int wm = w & 1, wn = w >> 1;
    const int x7 = lm & 7;
    const int sw0 = (q ^ x7) * 16;
    const int sw1 = ((4 + q) ^ x7) * 16;

    const __bf16* ga[2];
    const __bf16* gb[2];
#pragma unroll
    for (int j = 0; j < 2; j++) {
        int c = j * 256 + tid;
        int r = c >> 3;
        int ks = ((c & 7) ^ (r & 7)) * 8;
        ga[j] = act + (size_t)(base + m0 + r) * HDIM + ks;   // pad rows masked at epilogue
        gb[j] = w2e + (size_t)(n0 + r) * HDIM + ks;
    }

    f32x4 acc[2][2];
#pragma unroll
    for (int mt = 0; mt < 2; mt++)
#pragma unroll
        for (int nt = 0; nt < 2; nt++) acc[mt][nt] = (f32x4){0.f, 0.f, 0.f, 0.f};

    for (int k0 = 0; k0 < HDIM; k0 += 64) {
        __syncthreads();
#pragma unroll
        for (int j = 0; j < 2; j++) {
            int c = j * 256 + tid;
            GLOAD_LDS16(ga[j], (char*)&As[0][0] + c * 16);
            GLOAD_LDS16(gb[j], (char*)&Bs[0][0] + c * 16);
            ga[j] += 64; gb[j] += 64;
        }
        __syncthreads();
#pragma unroll
        for (int kh = 0; kh < 2; kh++) {
            const int sw = kh ? sw1 : sw0;
            bf16x8 af[2];
#pragma unroll
            for (int mt = 0; mt < 2; mt++)
                af[mt] = *(const bf16x8*)((const char*)&As[wm * 32 + mt * 16 + lm][0] + sw);
#pragma unroll
            for (int nt = 0; nt < 2; nt++) {
                bf16x8 bfr = *(const bf16x8*)((const char*)&Bs[wn * 32 + nt * 16 + lm][0] + sw);
#pragma unroll
                for (int mt = 0; mt < 2; mt++)
                    acc[mt][nt] = __builtin_amdgcn_mfma_f32_16x16x32_bf16(af[mt], bfr, acc[mt][nt], 0, 0, 0);
            }
        }
    }

    int pi[2][4];
    float pw[2][4];
#pragma unroll
    for (int mt = 0; mt < 2; mt++)
#pragma unroll
        for (int r = 0; r < 4; r++) {
            int gm = m0 + wm * 32 + mt * 16 + q * 4 + r;
            if (gm < cnt) {
                int pr = order[base + gm];
                pi[mt][r] = pr;
                pw[mt][r] = p[pr];
            } else pi[mt][r] = -1;
        }
#pragma unroll
    for (int mt = 0; mt < 2; mt++)
#pragma unroll
        for (int nt = 0; nt < 2; nt++) {
            int col = n0 + wn * 32 + nt * 16 + lm;
#pragma unroll
            for (int r = 0; r < 4; r++) {
                if (pi[mt][r] >= 0) {
                    int tok = pi[mt][r] >> 1;
                    atomicAdd(out + (size_t)tok * DDIM + col, pw[mt][r] * acc[mt][nt][r]);
                }
            }
        }
}

extern "C" void kernel_launch(void* const* d_in, const int* in_sizes, int n_in,
                              void* d_out, int out_size, void* d_ws, size_t ws_size,
                              hipStream_t stream) {
    (void)in_sizes; (void)n_in; (void)out_size; (void)ws_size;
    const float* x   = (const float*)d_in[0];
    const float* p   = (const float*)d_in[1];
    const int* eidx  = (const int*)d_in[2];
    const float* W1  = (const float*)d_in[3];
    const float* W2  = (const float*)d_in[4];
    float* out = (float*)d_out;

    char* ws = (char*)d_ws;
    int* wsi     = (int*)ws;
    __bf16* xb   = (__bf16*)(ws + XB_OFF);
    __bf16* w1t  = (__bf16*)(ws + W1T_OFF);
    __bf16* w2t  = (__bf16*)(ws + W2T_OFF);
    __bf16* act  = (__bf16*)(ws + ACT_OFF);

    prep_kernel<<<6152, 256, 0, stream>>>(x, W1, eidx, wsi, xb, w1t);
    // z<8: gemm1 (64m tiles); z in [8,11): 2048 W2-cvt tiles + 512 out-zero blocks
    gemm1_kernel<<<dim3(16, 64, 11), 256, 0, stream>>>(xb, w1t, wsi, act, W2, w2t, out);
    gemm2_kernel<<<dim3(16, 64, NEXP), 256, 0, stream>>>(act, w2t, wsi, p, out);
}